// Round 16
// baseline (926.273 us; speedup 1.0000x reference)
//
#include <hip/hip_runtime.h>
#include <hip/hip_bf16.h>

// Problem constants (match reference)
#define E_LINKS 131072
#define M_PAIRS 1048576
#define DDIM    64
#define GG      1024
#define RUNITS  256
#define TITER   8

typedef __attribute__((ext_vector_type(8))) short bf16x8;
typedef __attribute__((ext_vector_type(4))) float f32x4;
typedef __attribute__((ext_vector_type(16))) float f32x16;

// HW bf16 convert (RNE)
__device__ inline unsigned short f2bf(float f){
  __bf16 b = (__bf16)f;
  unsigned short u;
  __builtin_memcpy(&u, &b, 2);
  return u;
}
__device__ inline float bf2f(unsigned short u){
  union { unsigned int u; float f; } v; v.u = ((unsigned int)u) << 16; return v.f;
}
__device__ inline float selu_f(float x){
  return x > 0.f ? 1.0507009873554805f * x
                 : 1.7580993408473766f * (__expf(x) - 1.f);
}
__device__ inline float sigmoid_f(float x){ return 1.f / (1.f + __expf(-x)); }
__device__ inline float tanh_f(float x){
  float xc = fminf(fmaxf(x, -15.f), 15.f);
  float e2 = __expf(2.f * xc);
  return (e2 - 1.f) / (e2 + 1.f);
}

__device__ inline bf16x8 packbf8f(float4 u0, float4 u1){
  bf16x8 r;
  r[0] = (short)f2bf(u0.x); r[1] = (short)f2bf(u0.y);
  r[2] = (short)f2bf(u0.z); r[3] = (short)f2bf(u0.w);
  r[4] = (short)f2bf(u1.x); r[5] = (short)f2bf(u1.y);
  r[6] = (short)f2bf(u1.z); r[7] = (short)f2bf(u1.w);
  return r;
}

__device__ inline f32x16 zero16(){
  f32x16 v;
  #pragma unroll
  for (int i = 0; i < 16; i++) v[i] = 0.f;
  return v;
}

// ---------------- preprocessing ----------------

// Merged: zero counts + graph offsets + weight prep. 512 blocks x 256 threads.
__global__ __launch_bounds__(256) void k_misc(const int* __restrict__ gid,
    const float* __restrict__ W_msg,
    const float* __restrict__ gk, const float* __restrict__ grk,
    const float* __restrict__ bi, const float* __restrict__ br,
    int* __restrict__ counts, int* __restrict__ goffs,
    unsigned short* __restrict__ WzrT, unsigned short* __restrict__ WxhT,
    unsigned short* __restrict__ WhhT, unsigned short* __restrict__ WcT,
    float* __restrict__ bzr, float* __restrict__ bxh, float* __restrict__ bhh){
  int i = blockIdx.x * blockDim.x + threadIdx.x;
  counts[i] = 0;
  {
    int g = gid[i];
    int gp = (i == 0) ? -1 : gid[i - 1];
    for (int x = gp + 1; x <= g; x++) goffs[x] = i;
    if (i == E_LINKS - 1){
      for (int x = g + 1; x <= GG; x++) goffs[x] = E_LINKS;
    }
  }
  if (i < 16384){
    int c = i >> 7, k = i & 127;
    float v = (k < 64) ? gk[k * 192 + c] : grk[(k - 64) * 192 + c];
    WzrT[i] = f2bf(v);
  } else if (i < 20480){
    int j = i - 16384; int c = j >> 6, k = j & 63;
    WxhT[j] = f2bf(gk[k * 192 + 128 + c]);
  } else if (i < 24576){
    int j = i - 20480; int c = j >> 6, k = j & 63;
    WhhT[j] = f2bf(grk[k * 192 + 128 + c]);
  } else if (i < 32768){
    int j = i - 24576; int c = j >> 6, k = j & 63;
    float v = (c < 64) ? W_msg[k * 64 + c] : W_msg[(64 + k) * 64 + (c - 64)];
    WcT[j] = f2bf(v);
  } else if (i < 33024){
    int j = i - 32768;
    if (j < 128) bzr[j] = bi[j] + br[j];
    else if (j < 192) bxh[j - 128] = bi[j];
    else bhh[j - 192] = br[j - 64];
  }
}

__global__ void k_hist(const int* __restrict__ second, int* __restrict__ counts){
  int i = blockIdx.x * blockDim.x + threadIdx.x;
  if (i < M_PAIRS) atomicAdd(&counts[second[i]], 1);
}

__global__ __launch_bounds__(256) void k_scan_reduce(const int* __restrict__ counts,
    int* __restrict__ partials){
  __shared__ int s[256];
  int t = threadIdx.x;
  int i = blockIdx.x * 256 + t;
  s[t] = counts[i];
  __syncthreads();
  #pragma unroll
  for (int off = 128; off > 0; off >>= 1){
    if (t < off) s[t] += s[t + off];
    __syncthreads();
  }
  if (t == 0) partials[blockIdx.x] = s[0];
}

__global__ __launch_bounds__(512) void k_scan_part(int* __restrict__ partials){
  __shared__ int s[512];
  int t = threadIdx.x;
  int v = partials[t];
  s[t] = v;
  __syncthreads();
  for (int off = 1; off < 512; off <<= 1){
    int u = (t >= off) ? s[t - off] : 0;
    __syncthreads();
    s[t] += u;
    __syncthreads();
  }
  partials[t] = s[t] - v;
}

__global__ __launch_bounds__(256) void k_scan_apply(const int* __restrict__ counts,
    const int* __restrict__ partials, int* __restrict__ offsets,
    int* __restrict__ cursor){
  __shared__ int s[256];
  int t = threadIdx.x;
  int i = blockIdx.x * 256 + t;
  int c = counts[i];
  s[t] = c;
  __syncthreads();
  for (int off = 1; off < 256; off <<= 1){
    int u = (t >= off) ? s[t - off] : 0;
    __syncthreads();
    s[t] += u;
    __syncthreads();
  }
  int run = partials[blockIdx.x] + s[t] - c;
  offsets[i] = run;
  cursor[i] = run;
  if (i == E_LINKS - 1) offsets[E_LINKS] = run + c;
}

// Windowed scatter: 8 sequential passes; pass w handles pairs whose target
// edge is in window w (16384 edges) -> writes land in ~512KB (L2-resident).
__global__ __launch_bounds__(256) void k_scatter(const int* __restrict__ first,
    const int* __restrict__ second, int* __restrict__ cursor,
    int* __restrict__ srcs){
  int base = blockIdx.x * 1024;   // 1024 pairs per block (grid 1024)
  for (int w = 0; w < 8; w++){
    #pragma unroll
    for (int k = 0; k < 4; k++){
      int i = base + k * 256 + threadIdx.x;
      int e = second[i];
      if ((e >> 14) == w){
        int slot = atomicAdd(&cursor[e], 1);
        srcs[slot] = first[i];
      }
    }
  }
}

// ---------------- main loop kernels ----------------

// A[E,64] = h @ Wc[:, 0:64]; B[E,64] = h @ Wc[:, 64:128] + b_msg.
// Also initializes the bf16 h state.
__global__ __launch_bounds__(256) void k_ab0(const float* __restrict__ hf,
    const unsigned short* __restrict__ WcT, const float* __restrict__ b_msg,
    unsigned short* __restrict__ Ab, unsigned short* __restrict__ Bb,
    unsigned short* __restrict__ hb){
  int wave = threadIdx.x >> 6, lane = threadIdx.x & 63;
  int row0 = (blockIdx.x * 4 + wave) * 16;
  int lr = lane & 15, lg = lane >> 4;
  f32x4 acc[8];
  #pragma unroll
  for (int i = 0; i < 8; i++) acc[i] = (f32x4){0.f, 0.f, 0.f, 0.f};
  #pragma unroll
  for (int s = 0; s < 2; s++){
    int kb = s * 32 + lg * 8;
    const float* p = hf + (size_t)(row0 + lr) * 64 + kb;
    bf16x8 a = packbf8f(*(const float4*)p, *(const float4*)(p + 4));
    *(bf16x8*)(hb + (size_t)(row0 + lr) * 64 + kb) = a;   // h state init
    #pragma unroll
    for (int ct = 0; ct < 8; ct++){
      bf16x8 b = *(const bf16x8*)(WcT + (ct * 16 + lr) * 64 + kb);
      acc[ct] = __builtin_amdgcn_mfma_f32_16x16x32_bf16(a, b, acc[ct], 0, 0, 0);
    }
  }
  #pragma unroll
  for (int ct = 0; ct < 8; ct++){
    int col = ct * 16 + lr;
    #pragma unroll
    for (int q = 0; q < 4; q++){
      int row = row0 + lg * 4 + q;
      if (col < 64)
        Ab[(size_t)row * 64 + col] = f2bf(acc[ct][q]);
      else
        Bb[(size_t)row * 64 + (col - 64)] = f2bf(acc[ct][q] + b_msg[col - 64]);
    }
  }
}

// agg[e][:] = sum over incoming msgs: selu(A[src] + B[e])
__global__ __launch_bounds__(256) void k_agg(const unsigned short* __restrict__ Ab,
    const unsigned short* __restrict__ Bb,
    const int* __restrict__ offsets, const int* __restrict__ srcs,
    unsigned short* __restrict__ agg){
  int wave = threadIdx.x >> 6, lane = threadIdx.x & 63;
  int e = blockIdx.x * 4 + wave;
  int g = lane >> 4, d = lane & 15;

  ushort4 bq = *(const ushort4*)(Bb + (size_t)e * 64 + d * 4);
  float b0 = bf2f(bq.x), b1 = bf2f(bq.y), b2 = bf2f(bq.z), b3 = bf2f(bq.w);

  int beg = offsets[e], end = offsets[e + 1];
  float a0 = 0.f, a1 = 0.f, a2 = 0.f, a3 = 0.f;

  int i = beg + g;
  for (; i + 4 < end; i += 8){
    int s0 = srcs[i];
    int s1 = srcs[i + 4];
    ushort4 q0 = *(const ushort4*)(Ab + (size_t)s0 * 64 + d * 4);
    ushort4 q1 = *(const ushort4*)(Ab + (size_t)s1 * 64 + d * 4);
    a0 += selu_f(bf2f(q0.x) + b0);
    a1 += selu_f(bf2f(q0.y) + b1);
    a2 += selu_f(bf2f(q0.z) + b2);
    a3 += selu_f(bf2f(q0.w) + b3);
    a0 += selu_f(bf2f(q1.x) + b0);
    a1 += selu_f(bf2f(q1.y) + b1);
    a2 += selu_f(bf2f(q1.z) + b2);
    a3 += selu_f(bf2f(q1.w) + b3);
  }
  if (i < end){
    int s0 = srcs[i];
    ushort4 q0 = *(const ushort4*)(Ab + (size_t)s0 * 64 + d * 4);
    a0 += selu_f(bf2f(q0.x) + b0);
    a1 += selu_f(bf2f(q0.y) + b1);
    a2 += selu_f(bf2f(q0.z) + b2);
    a3 += selu_f(bf2f(q0.w) + b3);
  }

  a0 += __shfl_xor(a0, 16, 64); a0 += __shfl_xor(a0, 32, 64);
  a1 += __shfl_xor(a1, 16, 64); a1 += __shfl_xor(a1, 32, 64);
  a2 += __shfl_xor(a2, 16, 64); a2 += __shfl_xor(a2, 32, 64);
  a3 += __shfl_xor(a3, 16, 64); a3 += __shfl_xor(a3, 32, 64);

  if (g == 0){
    ushort4 o;
    o.x = f2bf(a0); o.y = f2bf(a1); o.z = f2bf(a2); o.w = f2bf(a3);
    *(ushort4*)(agg + (size_t)e * 64 + d * 4) = o;
  }
}

// Fused GRU (+ optional A/B production), 32 rows/wave via 32x32x16 MFMA.
// h state bf16, in place. LDS hold tile unioned with transpose tile.
// NEW (R16): all global write-backs (h, A, B) go through per-wave LDS tiles
// and leave as fully-coalesced bf16x8 stores (12 wide stores/thread instead
// of 96 scalar 2B stores).
template<bool WITH_AB>
__global__ __launch_bounds__(256, 4) void k_fused(const unsigned short* __restrict__ agg,
    unsigned short* h,
    const unsigned short* __restrict__ WzrT, const unsigned short* __restrict__ WxhT,
    const unsigned short* __restrict__ WhhT, const unsigned short* __restrict__ WcT,
    const float* __restrict__ bzr, const float* __restrict__ bxh,
    const float* __restrict__ bhh, const float* __restrict__ b_msg,
    unsigned short* __restrict__ Ab, unsigned short* __restrict__ Bb){
  __shared__ float hsh[4][32][68];   // 34816B; tail-reused as tsh / A,B tiles
  int wave = threadIdx.x >> 6, lane = threadIdx.x & 63;
  int row0 = (blockIdx.x * 4 + wave) * 32;
  int lc = lane & 31, lh = lane >> 5;
  unsigned short* tsh = (unsigned short*)&hsh[wave][0][0]; // [32][64] bf16, swizzled

  // ---- A fragments over combined K=128 ([agg | h]) + fp32 hold stash ----
  bf16x8 az[8];
  const unsigned short* arow = agg + (size_t)(row0 + lc) * 64 + lh * 8;
  #pragma unroll
  for (int s = 0; s < 4; s++) az[s] = *(const bf16x8*)(arow + s * 16);
  const unsigned short* hrow = h + (size_t)(row0 + lc) * 64 + lh * 8;
  #pragma unroll
  for (int s = 0; s < 4; s++){
    bf16x8 hv = *(const bf16x8*)(hrow + s * 16);
    az[4 + s] = hv;
    float4 u0, u1;
    u0.x = bf2f((unsigned short)hv[0]); u0.y = bf2f((unsigned short)hv[1]);
    u0.z = bf2f((unsigned short)hv[2]); u0.w = bf2f((unsigned short)hv[3]);
    u1.x = bf2f((unsigned short)hv[4]); u1.y = bf2f((unsigned short)hv[5]);
    u1.z = bf2f((unsigned short)hv[6]); u1.w = bf2f((unsigned short)hv[7]);
    *(float4*)(&hsh[wave][lc][s * 16 + lh * 8]) = u0;
    *(float4*)(&hsh[wave][lc][s * 16 + lh * 8 + 4]) = u1;
  }

  // ---- r-gate GEMM (zr tiles 2,3 -> cols 64..127) ----
  f32x16 ar0 = zero16(), ar1 = zero16();
  #pragma unroll
  for (int s = 0; s < 8; s++){
    const unsigned short* wk = WzrT + lh * 8 + s * 16;
    bf16x8 b2 = *(const bf16x8*)(wk + (size_t)(64 + lc) * 128);
    bf16x8 b3 = *(const bf16x8*)(wk + (size_t)(96 + lc) * 128);
    ar0 = __builtin_amdgcn_mfma_f32_32x32x16_bf16(az[s], b2, ar0, 0, 0, 0);
    ar1 = __builtin_amdgcn_mfma_f32_32x32x16_bf16(az[s], b3, ar1, 0, 0, 0);
  }

  float cv[2][16];

  // ---- cols 0..31: xh0 (A=agg), hh0 (A=h) -> cv[0] ----
  {
    f32x16 axh = zero16(), ahh = zero16();
    #pragma unroll
    for (int s = 0; s < 4; s++){
      const unsigned short* wx = WxhT + lh * 8 + s * 16;
      axh = __builtin_amdgcn_mfma_f32_32x32x16_bf16(az[s],
          *(const bf16x8*)(wx + (size_t)lc * 64), axh, 0, 0, 0);
      const unsigned short* wh = WhhT + lh * 8 + s * 16;
      ahh = __builtin_amdgcn_mfma_f32_32x32x16_bf16(az[4 + s],
          *(const bf16x8*)(wh + (size_t)lc * 64), ahh, 0, 0, 0);
    }
    float brv = bzr[64 + lc], bx = bxh[lc], bh = bhh[lc];
    #pragma unroll
    for (int r = 0; r < 16; r++){
      float rr = sigmoid_f(ar0[r] + brv);
      cv[0][r] = tanh_f(axh[r] + bx + rr * (ahh[r] + bh));
    }
  }

  // ---- cols 32..63: xh1, hh1 -> cv[1] ----
  {
    f32x16 axh = zero16(), ahh = zero16();
    #pragma unroll
    for (int s = 0; s < 4; s++){
      const unsigned short* wx = WxhT + lh * 8 + s * 16;
      axh = __builtin_amdgcn_mfma_f32_32x32x16_bf16(az[s],
          *(const bf16x8*)(wx + (size_t)(32 + lc) * 64), axh, 0, 0, 0);
      const unsigned short* wh = WhhT + lh * 8 + s * 16;
      ahh = __builtin_amdgcn_mfma_f32_32x32x16_bf16(az[4 + s],
          *(const bf16x8*)(wh + (size_t)(32 + lc) * 64), ahh, 0, 0, 0);
    }
    float brv = bzr[64 + 32 + lc], bx = bxh[32 + lc], bh = bhh[32 + lc];
    #pragma unroll
    for (int r = 0; r < 16; r++){
      float rr = sigmoid_f(ar1[r] + brv);
      cv[1][r] = tanh_f(axh[r] + bx + rr * (ahh[r] + bh));
    }
  }

  // ---- z-gate GEMM (zr tiles 0,1 -> cols 0..63) ----
  f32x16 azt0 = zero16(), azt1 = zero16();
  #pragma unroll
  for (int s = 0; s < 8; s++){
    const unsigned short* wk = WzrT + lh * 8 + s * 16;
    bf16x8 b0 = *(const bf16x8*)(wk + (size_t)lc * 128);
    bf16x8 b1 = *(const bf16x8*)(wk + (size_t)(32 + lc) * 128);
    azt0 = __builtin_amdgcn_mfma_f32_32x32x16_bf16(az[s], b0, azt0, 0, 0, 0);
    azt1 = __builtin_amdgcn_mfma_f32_32x32x16_bf16(az[s], b1, azt1, 0, 0, 0);
  }

  // ---- phase 1: read holds from hsh, fold z -> final v (into cv) ----
  {
    float bz0 = bzr[lc], bz1 = bzr[32 + lc];
    #pragma unroll
    for (int r = 0; r < 16; r++){
      int rl = (r & 3) + 8 * (r >> 2) + 4 * lh;
      float h0 = hsh[wave][rl][lc];
      float h1 = hsh[wave][rl][32 + lc];
      float z0 = sigmoid_f(azt0[r] + bz0);
      float z1 = sigmoid_f(azt1[r] + bz1);
      cv[0][r] = z0 * h0 + (1.f - z0) * cv[0][r];
      cv[1][r] = z1 * h1 + (1.f - z1) * cv[1][r];
    }
  }

  __syncthreads();   // all hsh reads complete before tsh overwrites the space

  // ---- phase 2: stash hn (swizzled bf16) in tsh; WIDE coalesced h store ----
  {
    int j0 = lc, j1 = 32 + lc;
    #pragma unroll
    for (int r = 0; r < 16; r++){
      int rl = (r & 3) + 8 * (r >> 2) + 4 * lh;
      tsh[rl * 64 + (((j0 >> 3) ^ (rl & 7)) << 3) + (j0 & 7)] = f2bf(cv[0][r]);
      tsh[rl * 64 + (((j1 >> 3) ^ (rl & 7)) << 3) + (j1 & 7)] = f2bf(cv[1][r]);
    }
    #pragma unroll
    for (int it = 0; it < 4; it++){
      int row = it * 8 + (lane >> 3), b = lane & 7;
      bf16x8 v = *(const bf16x8*)(&tsh[row * 64 + ((b ^ (row & 7)) << 3)]);
      *(bf16x8*)(h + (size_t)(row0 + row) * 64 + b * 8) = v;
    }
  }

  if (WITH_AB){
    // AB GEMM: M=32, N=128, K=64; A = hn from swizzled tsh
    f32x16 acc[4];
    #pragma unroll
    for (int i = 0; i < 4; i++) acc[i] = zero16();
    #pragma unroll
    for (int s = 0; s < 4; s++){
      int blk = ((s * 2 + lh) ^ (lc & 7)) << 3;
      bf16x8 a = *(const bf16x8*)(&tsh[lc * 64 + blk]);
      const unsigned short* wc = WcT + lh * 8 + s * 16;
      #pragma unroll
      for (int ct = 0; ct < 4; ct++){
        bf16x8 b = *(const bf16x8*)(wc + (size_t)(ct * 32 + lc) * 64);
        acc[ct] = __builtin_amdgcn_mfma_f32_32x32x16_bf16(a, b, acc[ct], 0, 0, 0);
      }
    }
    // epilogue: acc -> LDS A/B tiles (plain [32][64]) -> wide coalesced stores.
    // tsh's GEMM reads precede these writes in the in-order per-wave ds queue.
    unsigned short* ash2 = tsh;            // A tile, reuses tsh space (4KB)
    unsigned short* bsh2 = tsh + 2048;     // B tile (4KB); total 8KB <= 8704B region
    #pragma unroll
    for (int ct = 0; ct < 4; ct++){
      int colh = ct * 32 + lc;
      #pragma unroll
      for (int r = 0; r < 16; r++){
        int rl = (r & 3) + 8 * (r >> 2) + 4 * lh;
        if (ct < 2) ash2[rl * 64 + colh] = f2bf(acc[ct][r]);
        else        bsh2[rl * 64 + (colh - 64)] = f2bf(acc[ct][r] + b_msg[colh - 64]);
      }
    }
    #pragma unroll
    for (int it = 0; it < 4; it++){
      int row = it * 8 + (lane >> 3), b = lane & 7;
      size_t go = (size_t)(row0 + row) * 64 + b * 8;
      *(bf16x8*)(Ab + go) = *(const bf16x8*)(&ash2[row * 64 + b * 8]);
      *(bf16x8*)(Bb + go) = *(const bf16x8*)(&bsh2[row * 64 + b * 8]);
    }
  }
}

// ---------------- readout (segment sum fused into MLP) ----------------

__global__ __launch_bounds__(256) void k_mlp(const unsigned short* __restrict__ hb,
    const int* __restrict__ goffs,
    const float* __restrict__ W1, const float* __restrict__ b1,
    const float* __restrict__ W2, const float* __restrict__ b2,
    const float* __restrict__ W3, const float* __restrict__ b3,
    float* __restrict__ out){
  __shared__ float part[4][64];
  __shared__ float sg[64];
  __shared__ float sr1[256];
  __shared__ float sr2[256];
  __shared__ float wsum[4];
  int g = blockIdx.x, t = threadIdx.x;
  int wave = t >> 6, lane = t & 63;

  int beg = goffs[g], end = goffs[g + 1];
  float acc = 0.f;
  for (int e = beg + wave; e < end; e += 4) acc += bf2f(hb[(size_t)e * 64 + lane]);
  part[wave][lane] = acc;
  __syncthreads();
  if (t < 64) sg[t] = part[0][t] + part[1][t] + part[2][t] + part[3][t];
  __syncthreads();

  float a = b1[t];
  #pragma unroll
  for (int k = 0; k < 64; k++) a += sg[k] * W1[k * 256 + t];
  sr1[t] = selu_f(a);
  __syncthreads();
  float b = b2[t];
  for (int k = 0; k < 256; k++) b += sr1[k] * W2[k * 256 + t];
  sr2[t] = selu_f(b);
  __syncthreads();
  float v = sr2[t] * W3[t];
  for (int off = 32; off > 0; off >>= 1) v += __shfl_down(v, off, 64);
  if ((t & 63) == 0) wsum[t >> 6] = v;
  __syncthreads();
  if (t == 0) out[g] = wsum[0] + wsum[1] + wsum[2] + wsum[3] + b3[0];
}

// ---------------- host ----------------

static inline size_t alignup(size_t x){ return (x + 255) & ~(size_t)255; }

extern "C" void kernel_launch(void* const* d_in, const int* in_sizes, int n_in,
                              void* d_out, int out_size, void* d_ws, size_t ws_size,
                              hipStream_t stream) {
  const float* states_action = (const float*)d_in[0];
  const int*   graph_ids     = (const int*)d_in[1];
  const int*   first         = (const int*)d_in[2];
  const int*   second        = (const int*)d_in[3];
  const float* W_msg         = (const float*)d_in[5];
  const float* b_msg         = (const float*)d_in[6];
  const float* gk            = (const float*)d_in[7];
  const float* grk           = (const float*)d_in[8];
  const float* bi            = (const float*)d_in[9];
  const float* br            = (const float*)d_in[10];
  const float* W1            = (const float*)d_in[11];
  const float* b1            = (const float*)d_in[12];
  const float* W2            = (const float*)d_in[13];
  const float* b2            = (const float*)d_in[14];
  const float* W3            = (const float*)d_in[15];
  const float* b3            = (const float*)d_in[16];
  float* out = (float*)d_out;

  char* ws = (char*)d_ws;
  size_t off = 0;
  unsigned short* h_bf   = (unsigned short*)(ws + off); off += alignup((size_t)E_LINKS * 64 * 2);
  unsigned short* aggb   = (unsigned short*)(ws + off); off += alignup((size_t)E_LINKS * 64 * 2);
  unsigned short* Abuf   = (unsigned short*)(ws + off); off += alignup((size_t)E_LINKS * 64 * 2);
  unsigned short* Bbuf   = (unsigned short*)(ws + off); off += alignup((size_t)E_LINKS * 64 * 2);
  unsigned short* WzrT   = (unsigned short*)(ws + off); off += alignup(128 * 128 * 2);
  unsigned short* WxhT   = (unsigned short*)(ws + off); off += alignup(64 * 64 * 2);
  unsigned short* WhhT   = (unsigned short*)(ws + off); off += alignup(64 * 64 * 2);
  unsigned short* WcT    = (unsigned short*)(ws + off); off += alignup(128 * 64 * 2);
  float*          bzr    = (float*)(ws + off);          off += alignup(128 * 4);
  float*          bxhv   = (float*)(ws + off);          off += alignup(64 * 4);
  float*          bhhv   = (float*)(ws + off);          off += alignup(64 * 4);
  int*            counts = (int*)(ws + off);            off += alignup((size_t)E_LINKS * 4);
  int*            offs   = (int*)(ws + off);            off += alignup(((size_t)E_LINKS + 1) * 4);
  int*            cursor = (int*)(ws + off);            off += alignup((size_t)E_LINKS * 4);
  int*            srcs   = (int*)(ws + off);            off += alignup((size_t)M_PAIRS * 4);
  int*            parts  = (int*)(ws + off);            off += alignup(512 * 4);
  int*            goffs  = (int*)(ws + off);            off += alignup(((size_t)GG + 1) * 4);

  dim3 b256(256);

  // preprocessing
  k_misc<<<dim3(512), b256, 0, stream>>>(graph_ids, W_msg, gk, grk, bi, br,
      counts, goffs, WzrT, WxhT, WhhT, WcT, bzr, bxhv, bhhv);
  k_hist<<<dim3(M_PAIRS / 256), b256, 0, stream>>>(second, counts);
  k_scan_reduce<<<dim3(512), b256, 0, stream>>>(counts, parts);
  k_scan_part<<<dim3(1), dim3(512), 0, stream>>>(parts);
  k_scan_apply<<<dim3(512), b256, 0, stream>>>(counts, parts, offs, cursor);
  k_scatter<<<dim3(M_PAIRS / 1024), b256, 0, stream>>>(first, second, cursor, srcs);

  // t=0: A/B precompute + bf16 h init (fused)
  k_ab0<<<dim3(E_LINKS / 64), b256, 0, stream>>>(states_action, WcT, b_msg,
      Abuf, Bbuf, h_bf);

  // message passing: split kernels, single A/B buffers, in-place bf16 h
  for (int t = 0; t < TITER; t++){
    k_agg<<<dim3(E_LINKS / 4), b256, 0, stream>>>(Abuf, Bbuf, offs, srcs, aggb);
    if (t < TITER - 1)
      k_fused<true><<<dim3(E_LINKS / 128), b256, 0, stream>>>(aggb, h_bf,
          WzrT, WxhT, WhhT, WcT, bzr, bxhv, bhhv, b_msg, Abuf, Bbuf);
    else
      k_fused<false><<<dim3(E_LINKS / 128), b256, 0, stream>>>(aggb, h_bf,
          WzrT, WxhT, WhhT, WcT, bzr, bxhv, bhhv, b_msg, Abuf, Bbuf);
  }

  // readout
  k_mlp<<<dim3(GG), b256, 0, stream>>>(h_bf, goffs, W1, b1, W2, b2, W3, b3, out);
}

// Round 17
// 912.912 us; speedup vs baseline: 1.0146x; 1.0146x over previous
//
#include <hip/hip_runtime.h>
#include <hip/hip_bf16.h>

// Problem constants (match reference)
#define E_LINKS 131072
#define M_PAIRS 1048576
#define DDIM    64
#define GG      1024
#define RUNITS  256
#define TITER   8

typedef __attribute__((ext_vector_type(8))) short bf16x8;
typedef __attribute__((ext_vector_type(4))) float f32x4;
typedef __attribute__((ext_vector_type(16))) float f32x16;

// HW bf16 convert (RNE)
__device__ inline unsigned short f2bf(float f){
  __bf16 b = (__bf16)f;
  unsigned short u;
  __builtin_memcpy(&u, &b, 2);
  return u;
}
__device__ inline float bf2f(unsigned short u){
  union { unsigned int u; float f; } v; v.u = ((unsigned int)u) << 16; return v.f;
}
__device__ inline float selu_f(float x){
  return x > 0.f ? 1.0507009873554805f * x
                 : 1.7580993408473766f * (__expf(x) - 1.f);
}
__device__ inline float sigmoid_f(float x){ return 1.f / (1.f + __expf(-x)); }
__device__ inline float tanh_f(float x){
  float xc = fminf(fmaxf(x, -15.f), 15.f);
  float e2 = __expf(2.f * xc);
  return (e2 - 1.f) / (e2 + 1.f);
}

__device__ inline bf16x8 packbf8f(float4 u0, float4 u1){
  bf16x8 r;
  r[0] = (short)f2bf(u0.x); r[1] = (short)f2bf(u0.y);
  r[2] = (short)f2bf(u0.z); r[3] = (short)f2bf(u0.w);
  r[4] = (short)f2bf(u1.x); r[5] = (short)f2bf(u1.y);
  r[6] = (short)f2bf(u1.z); r[7] = (short)f2bf(u1.w);
  return r;
}

__device__ inline f32x16 zero16(){
  f32x16 v;
  #pragma unroll
  for (int i = 0; i < 16; i++) v[i] = 0.f;
  return v;
}

// ---------------- preprocessing ----------------

// Merged: zero counts + graph offsets + weight prep. 512 blocks x 256 threads.
__global__ __launch_bounds__(256) void k_misc(const int* __restrict__ gid,
    const float* __restrict__ W_msg,
    const float* __restrict__ gk, const float* __restrict__ grk,
    const float* __restrict__ bi, const float* __restrict__ br,
    int* __restrict__ counts, int* __restrict__ goffs,
    unsigned short* __restrict__ WzrT, unsigned short* __restrict__ WxhT,
    unsigned short* __restrict__ WhhT, unsigned short* __restrict__ WcT,
    float* __restrict__ bzr, float* __restrict__ bxh, float* __restrict__ bhh){
  int i = blockIdx.x * blockDim.x + threadIdx.x;
  counts[i] = 0;
  {
    int g = gid[i];
    int gp = (i == 0) ? -1 : gid[i - 1];
    for (int x = gp + 1; x <= g; x++) goffs[x] = i;
    if (i == E_LINKS - 1){
      for (int x = g + 1; x <= GG; x++) goffs[x] = E_LINKS;
    }
  }
  if (i < 16384){
    int c = i >> 7, k = i & 127;
    float v = (k < 64) ? gk[k * 192 + c] : grk[(k - 64) * 192 + c];
    WzrT[i] = f2bf(v);
  } else if (i < 20480){
    int j = i - 16384; int c = j >> 6, k = j & 63;
    WxhT[j] = f2bf(gk[k * 192 + 128 + c]);
  } else if (i < 24576){
    int j = i - 20480; int c = j >> 6, k = j & 63;
    WhhT[j] = f2bf(grk[k * 192 + 128 + c]);
  } else if (i < 32768){
    int j = i - 24576; int c = j >> 6, k = j & 63;
    float v = (c < 64) ? W_msg[k * 64 + c] : W_msg[(64 + k) * 64 + (c - 64)];
    WcT[j] = f2bf(v);
  } else if (i < 33024){
    int j = i - 32768;
    if (j < 128) bzr[j] = bi[j] + br[j];
    else if (j < 192) bxh[j - 128] = bi[j];
    else bhh[j - 192] = br[j - 64];
  }
}

__global__ void k_hist(const int* __restrict__ second, int* __restrict__ counts){
  int i = blockIdx.x * blockDim.x + threadIdx.x;
  if (i < M_PAIRS) atomicAdd(&counts[second[i]], 1);
}

__global__ __launch_bounds__(256) void k_scan_reduce(const int* __restrict__ counts,
    int* __restrict__ partials){
  __shared__ int s[256];
  int t = threadIdx.x;
  int i = blockIdx.x * 256 + t;
  s[t] = counts[i];
  __syncthreads();
  #pragma unroll
  for (int off = 128; off > 0; off >>= 1){
    if (t < off) s[t] += s[t + off];
    __syncthreads();
  }
  if (t == 0) partials[blockIdx.x] = s[0];
}

__global__ __launch_bounds__(512) void k_scan_part(int* __restrict__ partials){
  __shared__ int s[512];
  int t = threadIdx.x;
  int v = partials[t];
  s[t] = v;
  __syncthreads();
  for (int off = 1; off < 512; off <<= 1){
    int u = (t >= off) ? s[t - off] : 0;
    __syncthreads();
    s[t] += u;
    __syncthreads();
  }
  partials[t] = s[t] - v;
}

__global__ __launch_bounds__(256) void k_scan_apply(const int* __restrict__ counts,
    const int* __restrict__ partials, int* __restrict__ offsets,
    int* __restrict__ cursor){
  __shared__ int s[256];
  int t = threadIdx.x;
  int i = blockIdx.x * 256 + t;
  int c = counts[i];
  s[t] = c;
  __syncthreads();
  for (int off = 1; off < 256; off <<= 1){
    int u = (t >= off) ? s[t - off] : 0;
    __syncthreads();
    s[t] += u;
    __syncthreads();
  }
  int run = partials[blockIdx.x] + s[t] - c;
  offsets[i] = run;
  cursor[i] = run;
  if (i == E_LINKS - 1) offsets[E_LINKS] = run + c;
}

// Windowed scatter: 8 sequential passes; pass w handles pairs whose target
// edge is in window w (16384 edges) -> writes land in ~512KB (L2-resident).
__global__ __launch_bounds__(256) void k_scatter(const int* __restrict__ first,
    const int* __restrict__ second, int* __restrict__ cursor,
    int* __restrict__ srcs){
  int base = blockIdx.x * 1024;   // 1024 pairs per block (grid 1024)
  for (int w = 0; w < 8; w++){
    #pragma unroll
    for (int k = 0; k < 4; k++){
      int i = base + k * 256 + threadIdx.x;
      int e = second[i];
      if ((e >> 14) == w){
        int slot = atomicAdd(&cursor[e], 1);
        srcs[slot] = first[i];
      }
    }
  }
}

// ---------------- main loop kernels ----------------

// A[E,64] = h @ Wc[:, 0:64]; B[E,64] = h @ Wc[:, 64:128] + b_msg.
// Also initializes the bf16 h state.
__global__ __launch_bounds__(256) void k_ab0(const float* __restrict__ hf,
    const unsigned short* __restrict__ WcT, const float* __restrict__ b_msg,
    unsigned short* __restrict__ Ab, unsigned short* __restrict__ Bb,
    unsigned short* __restrict__ hb){
  int wave = threadIdx.x >> 6, lane = threadIdx.x & 63;
  int row0 = (blockIdx.x * 4 + wave) * 16;
  int lr = lane & 15, lg = lane >> 4;
  f32x4 acc[8];
  #pragma unroll
  for (int i = 0; i < 8; i++) acc[i] = (f32x4){0.f, 0.f, 0.f, 0.f};
  #pragma unroll
  for (int s = 0; s < 2; s++){
    int kb = s * 32 + lg * 8;
    const float* p = hf + (size_t)(row0 + lr) * 64 + kb;
    bf16x8 a = packbf8f(*(const float4*)p, *(const float4*)(p + 4));
    *(bf16x8*)(hb + (size_t)(row0 + lr) * 64 + kb) = a;   // h state init
    #pragma unroll
    for (int ct = 0; ct < 8; ct++){
      bf16x8 b = *(const bf16x8*)(WcT + (ct * 16 + lr) * 64 + kb);
      acc[ct] = __builtin_amdgcn_mfma_f32_16x16x32_bf16(a, b, acc[ct], 0, 0, 0);
    }
  }
  #pragma unroll
  for (int ct = 0; ct < 8; ct++){
    int col = ct * 16 + lr;
    #pragma unroll
    for (int q = 0; q < 4; q++){
      int row = row0 + lg * 4 + q;
      if (col < 64)
        Ab[(size_t)row * 64 + col] = f2bf(acc[ct][q]);
      else
        Bb[(size_t)row * 64 + (col - 64)] = f2bf(acc[ct][q] + b_msg[col - 64]);
    }
  }
}

// agg[e][:] = sum over incoming msgs: selu(A[src] + B[e])
__global__ __launch_bounds__(256) void k_agg(const unsigned short* __restrict__ Ab,
    const unsigned short* __restrict__ Bb,
    const int* __restrict__ offsets, const int* __restrict__ srcs,
    unsigned short* __restrict__ agg){
  int wave = threadIdx.x >> 6, lane = threadIdx.x & 63;
  int e = blockIdx.x * 4 + wave;
  int g = lane >> 4, d = lane & 15;

  ushort4 bq = *(const ushort4*)(Bb + (size_t)e * 64 + d * 4);
  float b0 = bf2f(bq.x), b1 = bf2f(bq.y), b2 = bf2f(bq.z), b3 = bf2f(bq.w);

  int beg = offsets[e], end = offsets[e + 1];
  float a0 = 0.f, a1 = 0.f, a2 = 0.f, a3 = 0.f;

  int i = beg + g;
  for (; i + 4 < end; i += 8){
    int s0 = srcs[i];
    int s1 = srcs[i + 4];
    ushort4 q0 = *(const ushort4*)(Ab + (size_t)s0 * 64 + d * 4);
    ushort4 q1 = *(const ushort4*)(Ab + (size_t)s1 * 64 + d * 4);
    a0 += selu_f(bf2f(q0.x) + b0);
    a1 += selu_f(bf2f(q0.y) + b1);
    a2 += selu_f(bf2f(q0.z) + b2);
    a3 += selu_f(bf2f(q0.w) + b3);
    a0 += selu_f(bf2f(q1.x) + b0);
    a1 += selu_f(bf2f(q1.y) + b1);
    a2 += selu_f(bf2f(q1.z) + b2);
    a3 += selu_f(bf2f(q1.w) + b3);
  }
  if (i < end){
    int s0 = srcs[i];
    ushort4 q0 = *(const ushort4*)(Ab + (size_t)s0 * 64 + d * 4);
    a0 += selu_f(bf2f(q0.x) + b0);
    a1 += selu_f(bf2f(q0.y) + b1);
    a2 += selu_f(bf2f(q0.z) + b2);
    a3 += selu_f(bf2f(q0.w) + b3);
  }

  a0 += __shfl_xor(a0, 16, 64); a0 += __shfl_xor(a0, 32, 64);
  a1 += __shfl_xor(a1, 16, 64); a1 += __shfl_xor(a1, 32, 64);
  a2 += __shfl_xor(a2, 16, 64); a2 += __shfl_xor(a2, 32, 64);
  a3 += __shfl_xor(a3, 16, 64); a3 += __shfl_xor(a3, 32, 64);

  if (g == 0){
    ushort4 o;
    o.x = f2bf(a0); o.y = f2bf(a1); o.z = f2bf(a2); o.w = f2bf(a3);
    *(ushort4*)(agg + (size_t)e * 64 + d * 4) = o;
  }
}

// Fused GRU (+ optional A/B production), 32 rows/wave via 32x32x16 MFMA.
// h state bf16, in place. LDS hold tile unioned with transpose tile.
template<bool WITH_AB>
__global__ __launch_bounds__(256, 4) void k_fused(const unsigned short* __restrict__ agg,
    unsigned short* h,
    const unsigned short* __restrict__ WzrT, const unsigned short* __restrict__ WxhT,
    const unsigned short* __restrict__ WhhT, const unsigned short* __restrict__ WcT,
    const float* __restrict__ bzr, const float* __restrict__ bxh,
    const float* __restrict__ bhh, const float* __restrict__ b_msg,
    unsigned short* __restrict__ Ab, unsigned short* __restrict__ Bb){
  __shared__ float hsh[4][32][68];   // 34816B; tail-reused as tsh
  int wave = threadIdx.x >> 6, lane = threadIdx.x & 63;
  int row0 = (blockIdx.x * 4 + wave) * 32;
  int lc = lane & 31, lh = lane >> 5;
  unsigned short* tsh = (unsigned short*)&hsh[wave][0][0]; // [32][64] bf16, swizzled

  // ---- A fragments over combined K=128 ([agg | h]) + fp32 hold stash ----
  bf16x8 az[8];
  const unsigned short* arow = agg + (size_t)(row0 + lc) * 64 + lh * 8;
  #pragma unroll
  for (int s = 0; s < 4; s++) az[s] = *(const bf16x8*)(arow + s * 16);
  const unsigned short* hrow = h + (size_t)(row0 + lc) * 64 + lh * 8;
  #pragma unroll
  for (int s = 0; s < 4; s++){
    bf16x8 hv = *(const bf16x8*)(hrow + s * 16);
    az[4 + s] = hv;
    float4 u0, u1;
    u0.x = bf2f((unsigned short)hv[0]); u0.y = bf2f((unsigned short)hv[1]);
    u0.z = bf2f((unsigned short)hv[2]); u0.w = bf2f((unsigned short)hv[3]);
    u1.x = bf2f((unsigned short)hv[4]); u1.y = bf2f((unsigned short)hv[5]);
    u1.z = bf2f((unsigned short)hv[6]); u1.w = bf2f((unsigned short)hv[7]);
    *(float4*)(&hsh[wave][lc][s * 16 + lh * 8]) = u0;
    *(float4*)(&hsh[wave][lc][s * 16 + lh * 8 + 4]) = u1;
  }

  // ---- r-gate GEMM (zr tiles 2,3 -> cols 64..127) ----
  f32x16 ar0 = zero16(), ar1 = zero16();
  #pragma unroll
  for (int s = 0; s < 8; s++){
    const unsigned short* wk = WzrT + lh * 8 + s * 16;
    bf16x8 b2 = *(const bf16x8*)(wk + (size_t)(64 + lc) * 128);
    bf16x8 b3 = *(const bf16x8*)(wk + (size_t)(96 + lc) * 128);
    ar0 = __builtin_amdgcn_mfma_f32_32x32x16_bf16(az[s], b2, ar0, 0, 0, 0);
    ar1 = __builtin_amdgcn_mfma_f32_32x32x16_bf16(az[s], b3, ar1, 0, 0, 0);
  }

  float cv[2][16];

  // ---- cols 0..31: xh0 (A=agg), hh0 (A=h) -> cv[0] ----
  {
    f32x16 axh = zero16(), ahh = zero16();
    #pragma unroll
    for (int s = 0; s < 4; s++){
      const unsigned short* wx = WxhT + lh * 8 + s * 16;
      axh = __builtin_amdgcn_mfma_f32_32x32x16_bf16(az[s],
          *(const bf16x8*)(wx + (size_t)lc * 64), axh, 0, 0, 0);
      const unsigned short* wh = WhhT + lh * 8 + s * 16;
      ahh = __builtin_amdgcn_mfma_f32_32x32x16_bf16(az[4 + s],
          *(const bf16x8*)(wh + (size_t)lc * 64), ahh, 0, 0, 0);
    }
    float brv = bzr[64 + lc], bx = bxh[lc], bh = bhh[lc];
    #pragma unroll
    for (int r = 0; r < 16; r++){
      float rr = sigmoid_f(ar0[r] + brv);
      cv[0][r] = tanh_f(axh[r] + bx + rr * (ahh[r] + bh));
    }
  }

  // ---- cols 32..63: xh1, hh1 -> cv[1] ----
  {
    f32x16 axh = zero16(), ahh = zero16();
    #pragma unroll
    for (int s = 0; s < 4; s++){
      const unsigned short* wx = WxhT + lh * 8 + s * 16;
      axh = __builtin_amdgcn_mfma_f32_32x32x16_bf16(az[s],
          *(const bf16x8*)(wx + (size_t)(32 + lc) * 64), axh, 0, 0, 0);
      const unsigned short* wh = WhhT + lh * 8 + s * 16;
      ahh = __builtin_amdgcn_mfma_f32_32x32x16_bf16(az[4 + s],
          *(const bf16x8*)(wh + (size_t)(32 + lc) * 64), ahh, 0, 0, 0);
    }
    float brv = bzr[64 + 32 + lc], bx = bxh[32 + lc], bh = bhh[32 + lc];
    #pragma unroll
    for (int r = 0; r < 16; r++){
      float rr = sigmoid_f(ar1[r] + brv);
      cv[1][r] = tanh_f(axh[r] + bx + rr * (ahh[r] + bh));
    }
  }

  // ---- z-gate GEMM (zr tiles 0,1 -> cols 0..63) ----
  f32x16 azt0 = zero16(), azt1 = zero16();
  #pragma unroll
  for (int s = 0; s < 8; s++){
    const unsigned short* wk = WzrT + lh * 8 + s * 16;
    bf16x8 b0 = *(const bf16x8*)(wk + (size_t)lc * 128);
    bf16x8 b1 = *(const bf16x8*)(wk + (size_t)(32 + lc) * 128);
    azt0 = __builtin_amdgcn_mfma_f32_32x32x16_bf16(az[s], b0, azt0, 0, 0, 0);
    azt1 = __builtin_amdgcn_mfma_f32_32x32x16_bf16(az[s], b1, azt1, 0, 0, 0);
  }

  // ---- phase 1: read holds from hsh, fold z -> final v (into cv) ----
  {
    float bz0 = bzr[lc], bz1 = bzr[32 + lc];
    #pragma unroll
    for (int r = 0; r < 16; r++){
      int rl = (r & 3) + 8 * (r >> 2) + 4 * lh;
      float h0 = hsh[wave][rl][lc];
      float h1 = hsh[wave][rl][32 + lc];
      float z0 = sigmoid_f(azt0[r] + bz0);
      float z1 = sigmoid_f(azt1[r] + bz1);
      cv[0][r] = z0 * h0 + (1.f - z0) * cv[0][r];
      cv[1][r] = z1 * h1 + (1.f - z1) * cv[1][r];
    }
  }

  __syncthreads();   // all hsh reads complete before tsh overwrites the space

  // ---- phase 2: write h (bf16, in place) + tsh (LDS, swizzled) ----
  {
    int j0 = lc, j1 = 32 + lc;
    #pragma unroll
    for (int r = 0; r < 16; r++){
      int rl = (r & 3) + 8 * (r >> 2) + 4 * lh;
      size_t base = (size_t)(row0 + rl) * 64;
      unsigned short v0 = f2bf(cv[0][r]);
      unsigned short v1 = f2bf(cv[1][r]);
      h[base + j0] = v0;
      h[base + j1] = v1;
      if (WITH_AB){
        tsh[rl * 64 + (((j0 >> 3) ^ (rl & 7)) << 3) + (j0 & 7)] = v0;
        tsh[rl * 64 + (((j1 >> 3) ^ (rl & 7)) << 3) + (j1 & 7)] = v1;
      }
    }
  }

  if (WITH_AB){
    // AB GEMM: M=32, N=128, K=64; A = hn from swizzled tsh
    f32x16 acc[4];
    #pragma unroll
    for (int i = 0; i < 4; i++) acc[i] = zero16();
    #pragma unroll
    for (int s = 0; s < 4; s++){
      int blk = ((s * 2 + lh) ^ (lc & 7)) << 3;
      bf16x8 a = *(const bf16x8*)(&tsh[lc * 64 + blk]);
      const unsigned short* wc = WcT + lh * 8 + s * 16;
      #pragma unroll
      for (int ct = 0; ct < 4; ct++){
        bf16x8 b = *(const bf16x8*)(wc + (size_t)(ct * 32 + lc) * 64);
        acc[ct] = __builtin_amdgcn_mfma_f32_32x32x16_bf16(a, b, acc[ct], 0, 0, 0);
      }
    }
    #pragma unroll
    for (int ct = 0; ct < 4; ct++){
      int colh = ct * 32 + lc;           // 0..127 global col
      #pragma unroll
      for (int r = 0; r < 16; r++){
        int rl = (r & 3) + 8 * (r >> 2) + 4 * lh;
        size_t row = (size_t)(row0 + rl);
        if (ct < 2)
          Ab[row * 64 + colh] = f2bf(acc[ct][r]);
        else
          Bb[row * 64 + (colh - 64)] = f2bf(acc[ct][r] + b_msg[colh - 64]);
      }
    }
  }
}

// ---------------- readout (segment sum fused into MLP) ----------------

__global__ __launch_bounds__(256) void k_mlp(const unsigned short* __restrict__ hb,
    const int* __restrict__ goffs,
    const float* __restrict__ W1, const float* __restrict__ b1,
    const float* __restrict__ W2, const float* __restrict__ b2,
    const float* __restrict__ W3, const float* __restrict__ b3,
    float* __restrict__ out){
  __shared__ float part[4][64];
  __shared__ float sg[64];
  __shared__ float sr1[256];
  __shared__ float sr2[256];
  __shared__ float wsum[4];
  int g = blockIdx.x, t = threadIdx.x;
  int wave = t >> 6, lane = t & 63;

  int beg = goffs[g], end = goffs[g + 1];
  float acc = 0.f;
  for (int e = beg + wave; e < end; e += 4) acc += bf2f(hb[(size_t)e * 64 + lane]);
  part[wave][lane] = acc;
  __syncthreads();
  if (t < 64) sg[t] = part[0][t] + part[1][t] + part[2][t] + part[3][t];
  __syncthreads();

  float a = b1[t];
  #pragma unroll
  for (int k = 0; k < 64; k++) a += sg[k] * W1[k * 256 + t];
  sr1[t] = selu_f(a);
  __syncthreads();
  float b = b2[t];
  for (int k = 0; k < 256; k++) b += sr1[k] * W2[k * 256 + t];
  sr2[t] = selu_f(b);
  __syncthreads();
  float v = sr2[t] * W3[t];
  for (int off = 32; off > 0; off >>= 1) v += __shfl_down(v, off, 64);
  if ((t & 63) == 0) wsum[t >> 6] = v;
  __syncthreads();
  if (t == 0) out[g] = wsum[0] + wsum[1] + wsum[2] + wsum[3] + b3[0];
}

// ---------------- host ----------------

static inline size_t alignup(size_t x){ return (x + 255) & ~(size_t)255; }

extern "C" void kernel_launch(void* const* d_in, const int* in_sizes, int n_in,
                              void* d_out, int out_size, void* d_ws, size_t ws_size,
                              hipStream_t stream) {
  const float* states_action = (const float*)d_in[0];
  const int*   graph_ids     = (const int*)d_in[1];
  const int*   first         = (const int*)d_in[2];
  const int*   second        = (const int*)d_in[3];
  const float* W_msg         = (const float*)d_in[5];
  const float* b_msg         = (const float*)d_in[6];
  const float* gk            = (const float*)d_in[7];
  const float* grk           = (const float*)d_in[8];
  const float* bi            = (const float*)d_in[9];
  const float* br            = (const float*)d_in[10];
  const float* W1            = (const float*)d_in[11];
  const float* b1            = (const float*)d_in[12];
  const float* W2            = (const float*)d_in[13];
  const float* b2            = (const float*)d_in[14];
  const float* W3            = (const float*)d_in[15];
  const float* b3            = (const float*)d_in[16];
  float* out = (float*)d_out;

  char* ws = (char*)d_ws;
  size_t off = 0;
  unsigned short* h_bf   = (unsigned short*)(ws + off); off += alignup((size_t)E_LINKS * 64 * 2);
  unsigned short* aggb   = (unsigned short*)(ws + off); off += alignup((size_t)E_LINKS * 64 * 2);
  unsigned short* Abuf   = (unsigned short*)(ws + off); off += alignup((size_t)E_LINKS * 64 * 2);
  unsigned short* Bbuf   = (unsigned short*)(ws + off); off += alignup((size_t)E_LINKS * 64 * 2);
  unsigned short* WzrT   = (unsigned short*)(ws + off); off += alignup(128 * 128 * 2);
  unsigned short* WxhT   = (unsigned short*)(ws + off); off += alignup(64 * 64 * 2);
  unsigned short* WhhT   = (unsigned short*)(ws + off); off += alignup(64 * 64 * 2);
  unsigned short* WcT    = (unsigned short*)(ws + off); off += alignup(128 * 64 * 2);
  float*          bzr    = (float*)(ws + off);          off += alignup(128 * 4);
  float*          bxhv   = (float*)(ws + off);          off += alignup(64 * 4);
  float*          bhhv   = (float*)(ws + off);          off += alignup(64 * 4);
  int*            counts = (int*)(ws + off);            off += alignup((size_t)E_LINKS * 4);
  int*            offs   = (int*)(ws + off);            off += alignup(((size_t)E_LINKS + 1) * 4);
  int*            cursor = (int*)(ws + off);            off += alignup((size_t)E_LINKS * 4);
  int*            srcs   = (int*)(ws + off);            off += alignup((size_t)M_PAIRS * 4);
  int*            parts  = (int*)(ws + off);            off += alignup(512 * 4);
  int*            goffs  = (int*)(ws + off);            off += alignup(((size_t)GG + 1) * 4);

  dim3 b256(256);

  // preprocessing
  k_misc<<<dim3(512), b256, 0, stream>>>(graph_ids, W_msg, gk, grk, bi, br,
      counts, goffs, WzrT, WxhT, WhhT, WcT, bzr, bxhv, bhhv);
  k_hist<<<dim3(M_PAIRS / 256), b256, 0, stream>>>(second, counts);
  k_scan_reduce<<<dim3(512), b256, 0, stream>>>(counts, parts);
  k_scan_part<<<dim3(1), dim3(512), 0, stream>>>(parts);
  k_scan_apply<<<dim3(512), b256, 0, stream>>>(counts, parts, offs, cursor);
  k_scatter<<<dim3(M_PAIRS / 1024), b256, 0, stream>>>(first, second, cursor, srcs);

  // t=0: A/B precompute + bf16 h init (fused)
  k_ab0<<<dim3(E_LINKS / 64), b256, 0, stream>>>(states_action, WcT, b_msg,
      Abuf, Bbuf, h_bf);

  // message passing: split kernels, single A/B buffers, in-place bf16 h
  for (int t = 0; t < TITER; t++){
    k_agg<<<dim3(E_LINKS / 4), b256, 0, stream>>>(Abuf, Bbuf, offs, srcs, aggb);
    if (t < TITER - 1)
      k_fused<true><<<dim3(E_LINKS / 128), b256, 0, stream>>>(aggb, h_bf,
          WzrT, WxhT, WhhT, WcT, bzr, bxhv, bhhv, b_msg, Abuf, Bbuf);
    else
      k_fused<false><<<dim3(E_LINKS / 128), b256, 0, stream>>>(aggb, h_bf,
          WzrT, WxhT, WhhT, WcT, bzr, bxhv, bhhv, b_msg, Abuf, Bbuf);
  }

  // readout
  k_mlp<<<dim3(GG), b256, 0, stream>>>(h_bf, goffs, W1, b1, W2, b2, W3, b3, out);
}